// Round 39
// baseline (137.847 us; speedup 1.0000x reference)
//
#include <hip/hip_runtime.h>
#include <hip/hip_bf16.h>

typedef __attribute__((ext_vector_type(8))) short short8;
typedef __attribute__((ext_vector_type(4))) float f32x4;
typedef __attribute__((ext_vector_type(8))) unsigned short ushort8;

__device__ __forceinline__ unsigned short f32_to_bf16(float f) {
  return __builtin_bit_cast(unsigned short, __float2bfloat16(f));
}
__device__ __forceinline__ float bf16_to_f32(unsigned short u) {
  return __builtin_bit_cast(float, (unsigned)u << 16);
}

// global -> LDS direct async copy, 16 B per lane
__device__ __forceinline__ void gload_lds16(const unsigned short* g, unsigned short* l) {
  __builtin_amdgcn_global_load_lds((const __attribute__((address_space(1))) void*)g,
                                   (__attribute__((address_space(3))) void*)l, 16, 0, 0);
}

// ---------------- fused W [K][N] f32 -> WT [N][K] bf16, 4 weights ----------------
__global__ __launch_bounds__(256) void transpose4_kernel(const float* __restrict__ W0,
                                                         const float* __restrict__ W1,
                                                         const float* __restrict__ W2,
                                                         const float* __restrict__ W3,
                                                         unsigned short* __restrict__ T0,
                                                         unsigned short* __restrict__ T1,
                                                         unsigned short* __restrict__ T2,
                                                         unsigned short* __restrict__ T3) {
  __shared__ float t[32][33];
  const int D = 1024;
  const float* Ws[4] = {W0, W1, W2, W3};
  unsigned short* Ts[4] = {T0, T1, T2, T3};
  const float* W = Ws[blockIdx.z];
  unsigned short* WT = Ts[blockIdx.z];
  int bx = blockIdx.x, by = blockIdx.y;
  int tx = threadIdx.x, ty = threadIdx.y;
#pragma unroll
  for (int i = 0; i < 4; ++i)
    t[ty * 4 + i][tx] = W[(size_t)(by * 32 + ty * 4 + i) * D + bx * 32 + tx];
  __syncthreads();
#pragma unroll
  for (int i = 0; i < 4; ++i) {
    int r = ty * 4 + i;
    WT[(size_t)(bx * 32 + r) * D + by * 32 + tx] = f32_to_bf16(t[tx][r]);
  }
}

// ---------------- GEMM body: C[M][N] = A[M][K] @ Bt[N][K]^T + bias ----------------
// BM=64 x BN=128 tile, 512 threads = 8 waves (wm: 2 x 32 rows, wn: 4 x 32 cols).
// BK: K-step (64 or 128). BK=128 halves barrier count; use on grid-limited GEMMs.
// A_F32: A is raw f32; staged via reg + RNE cvt + ds_write (same swizzled layout).
// LN_A: A is bf16 PRE-LayerNorm; staging applies (x-mu)*rs*g+b with per-row MR={mu,rs}
//       (stats precomputed by ln_stats_kernel); residual in epilogue gets same LN
//       + explicit bf16 round so numerics match the former separate-ln0 pipeline.
// GELU_RES: out = res + gelu(C+bias), res = LN_A ? ln0(res16) : res16.
// o16_scale: multiplied into the bf16 output only.
// outT (optional): bf16 head-transposed V output with PV-fragment column permutation:
//   within each 64-block, k -> (nf>>1)*32 + lg*8 + (nf&1)*4 + j  (nf=k>>4, lg=(k>>2)&3, j=k&3)
template <bool GELU_RES, bool A_F32, bool LN_A, int BK>
__device__ __forceinline__ void gemm_body(const void* __restrict__ Av,
                                          const unsigned short* __restrict__ Bt,
                                          const float* __restrict__ bias,
                                          const unsigned short* __restrict__ res16,
                                          float* __restrict__ out32,
                                          unsigned short* __restrict__ out16,
                                          unsigned short* __restrict__ outT,
                                          const float2* __restrict__ MR,
                                          const float* __restrict__ lng,
                                          const float* __restrict__ lnb,
                                          float o16_scale,
                                          int M, int N, int K,
                                          unsigned short* As, unsigned short* Bs) {
  const int tid = threadIdx.x;
  const int lane = tid & 63, wid = tid >> 6;
  const int wm = wid >> 2, wn = wid & 3;
  const int m0 = blockIdx.x * 64, n0 = blockIdx.y * 128;
  const int lr = lane & 15, lg = lane >> 4;
  const int xs = lr & 7;
  const int CPR = BK / 8;                // 16B chunks per row
  f32x4 acc[2][2] = {};
  for (int kt = 0; kt < K; kt += BK) {
#pragma unroll
    for (int i = 0; i < (128 * CPR) / 512; ++i) {  // B: 128 rows x CPR chunks
      int c = tid + i * 512;
      int r = c / CPR, pc = c % CPR;
      int lc = (pc & ~7) | ((pc & 7) ^ (r & 7));
      gload_lds16(Bt + (size_t)(n0 + r) * K + kt + lc * 8, Bs + c * 8);
    }
#pragma unroll
    for (int i = 0; i < (64 * CPR) / 512; ++i) {   // A: 64 rows x CPR chunks
      int c = tid + i * 512;
      int r = c / CPR, pc = c % CPR;
      int lc = (pc & ~7) | ((pc & 7) ^ (r & 7));
      if (A_F32) {
        const float* src = (const float*)Av + (size_t)(m0 + r) * K + kt + lc * 8;
        float4 f0 = *(const float4*)(src);
        float4 f1 = *(const float4*)(src + 4);
        ushort8 o;
        o[0] = f32_to_bf16(f0.x); o[1] = f32_to_bf16(f0.y);
        o[2] = f32_to_bf16(f0.z); o[3] = f32_to_bf16(f0.w);
        o[4] = f32_to_bf16(f1.x); o[5] = f32_to_bf16(f1.y);
        o[6] = f32_to_bf16(f1.z); o[7] = f32_to_bf16(f1.w);
        *(ushort8*)(As + c * 8) = o;
      } else if (LN_A) {
        const unsigned short* src =
            (const unsigned short*)Av + (size_t)(m0 + r) * K + kt + lc * 8;
        ushort8 x = *(const ushort8*)src;
        float2 mr = MR[m0 + r];
        int col0 = kt + lc * 8;
        float4 ga = *(const float4*)(lng + col0);
        float4 gb = *(const float4*)(lng + col0 + 4);
        float4 ba = *(const float4*)(lnb + col0);
        float4 bb = *(const float4*)(lnb + col0 + 4);
        ushort8 o;
        o[0] = f32_to_bf16((bf16_to_f32(x[0]) - mr.x) * mr.y * ga.x + ba.x);
        o[1] = f32_to_bf16((bf16_to_f32(x[1]) - mr.x) * mr.y * ga.y + ba.y);
        o[2] = f32_to_bf16((bf16_to_f32(x[2]) - mr.x) * mr.y * ga.z + ba.z);
        o[3] = f32_to_bf16((bf16_to_f32(x[3]) - mr.x) * mr.y * ga.w + ba.w);
        o[4] = f32_to_bf16((bf16_to_f32(x[4]) - mr.x) * mr.y * gb.x + bb.x);
        o[5] = f32_to_bf16((bf16_to_f32(x[5]) - mr.x) * mr.y * gb.y + bb.y);
        o[6] = f32_to_bf16((bf16_to_f32(x[6]) - mr.x) * mr.y * gb.z + bb.z);
        o[7] = f32_to_bf16((bf16_to_f32(x[7]) - mr.x) * mr.y * gb.w + bb.w);
        *(ushort8*)(As + c * 8) = o;
      } else {
        gload_lds16((const unsigned short*)Av + (size_t)(m0 + r) * K + kt + lc * 8,
                    As + c * 8);
      }
    }
    __syncthreads();
#pragma unroll
    for (int ks = 0; ks < BK / 32; ++ks) {
      short8 af[2], bfr[2];
      int ch = ks * 4 + lg;                        // logical chunk 0..CPR-1
      int chs = (ch & ~7) | ((ch & 7) ^ xs);       // swizzled chunk
#pragma unroll
      for (int mf = 0; mf < 2; ++mf)
        af[mf] = *(const short8*)(As + (wm * 32 + mf * 16 + lr) * BK + (chs << 3));
#pragma unroll
      for (int nf = 0; nf < 2; ++nf)
        bfr[nf] = *(const short8*)(Bs + (wn * 32 + nf * 16 + lr) * BK + (chs << 3));
#pragma unroll
      for (int mf = 0; mf < 2; ++mf)
#pragma unroll
        for (int nf = 0; nf < 2; ++nf)
          acc[mf][nf] = __builtin_amdgcn_mfma_f32_16x16x32_bf16(af[mf], bfr[nf], acc[mf][nf], 0, 0, 0);
    }
    __syncthreads();
  }
#pragma unroll
  for (int nf = 0; nf < 2; ++nf) {
    int cn = n0 + wn * 32 + nf * 16 + lr;
    float bv = bias[cn];
    float gcn = 0.f, bcn = 0.f;
    if (GELU_RES && LN_A) { gcn = lng[cn]; bcn = lnb[cn]; }
#pragma unroll
    for (int mf = 0; mf < 2; ++mf) {
      int rm0 = m0 + wm * 32 + mf * 16 + lg * 4;
      float vv[4];
#pragma unroll
      for (int j = 0; j < 4; ++j) {
        float v = acc[mf][nf][j] + bv;
        if (GELU_RES) {
          float g = 0.5f * v * (1.0f + erff(v * 0.70710678118f));
          float resv;
          if (LN_A) {
            float xo = bf16_to_f32(res16[(size_t)(rm0 + j) * N + cn]);
            float2 mr = MR[rm0 + j];
            float o1 = (xo - mr.x) * mr.y * gcn + bcn;
            resv = bf16_to_f32(f32_to_bf16(o1));   // match former O1_16 bf16 round
          } else {
            resv = bf16_to_f32(res16[(size_t)(rm0 + j) * N + cn]);
          }
          v = resv + g;
        }
        vv[j] = v;
        if (out32) out32[(size_t)(rm0 + j) * N + cn] = v;
        if (out16) out16[(size_t)(rm0 + j) * N + cn] = f32_to_bf16(v * o16_scale);
      }
      if (outT) {
        // C^T[cn][rm0..rm0+3] -> VpT[(b*16+h)*64+d][kperm], b=rm>>11, k=rm&2047
        int bb = rm0 >> 11, kk = rm0 & 2047;
        int hh = cn >> 6, dd = cn & 63;
        int kin = kk & 63, kb = kk & ~63;
        int nfk = kin >> 4, lgk = (kin >> 2) & 3;
        int kperm = kb + (nfk >> 1) * 32 + lgk * 8 + (nfk & 1) * 4;
        ushort4 tv;
        tv.x = f32_to_bf16(vv[0]); tv.y = f32_to_bf16(vv[1]);
        tv.z = f32_to_bf16(vv[2]); tv.w = f32_to_bf16(vv[3]);
        *(ushort4*)(outT + ((size_t)((bb * 16 + hh) * 64 + dd)) * 2048 + kperm) = tv;
      }
    }
  }
}

// BK=128 variant: used for the Wv GEMM (grid 512 = 2 blocks/CU, grid-limited,
// so the 48 KB LDS costs no occupancy; barriers per K-loop halve).
template <bool GELU_RES>
__global__ __launch_bounds__(512) void gemm_kernel(const unsigned short* __restrict__ A,
                                                   const unsigned short* __restrict__ Bt,
                                                   const float* __restrict__ bias,
                                                   const unsigned short* __restrict__ res16,
                                                   float* __restrict__ out32,
                                                   unsigned short* __restrict__ out16,
                                                   unsigned short* __restrict__ outT,
                                                   int M, int N, int K) {
  __shared__ unsigned short As[64 * 128];
  __shared__ unsigned short Bs[128 * 128];
  gemm_body<GELU_RES, false, false, 128>(A, Bt, bias, res16, out32, out16, outT,
                                         nullptr, nullptr, nullptr, 1.0f,
                                         M, N, K, As, Bs);
}

// Wo GEMM with ln0 FUSED: A = ln0(O16) computed in staging, residual = ln0(O16)
// in epilogue (MR = per-row {mu,rs} from ln_stats_kernel).
__global__ __launch_bounds__(512) void gemm_lnwo_kernel(const unsigned short* __restrict__ A,
                                                        const unsigned short* __restrict__ Bt,
                                                        const float* __restrict__ bias,
                                                        unsigned short* __restrict__ out16,
                                                        const float2* __restrict__ MR,
                                                        const float* __restrict__ lng,
                                                        const float* __restrict__ lnb,
                                                        int M, int N, int K) {
  __shared__ unsigned short As[64 * 128];
  __shared__ unsigned short Bs[128 * 128];
  gemm_body<true, false, true, 128>(A, Bt, bias, A, nullptr, out16, nullptr,
                                    MR, lng, lnb, 1.0f, M, N, K, As, Bs);
}

// fused Q-proj + K-proj reading RAW f32 Q/K (conversion fused into A-staging);
// BK=64 (grid 1024 = 4 blocks/CU wants small LDS).
// Q's bf16 output pre-scaled by 0.125*log2(e) for attn (residual recovered by /SCALE2).
__global__ __launch_bounds__(512) void gemm_qk_kernel(const float* __restrict__ A0,
                                                      const float* __restrict__ A1,
                                                      const unsigned short* __restrict__ B0,
                                                      const unsigned short* __restrict__ B1,
                                                      const float* __restrict__ bias0,
                                                      const float* __restrict__ bias1,
                                                      unsigned short* __restrict__ o16_0,
                                                      unsigned short* __restrict__ o16_1,
                                                      int M, int N, int K) {
  __shared__ unsigned short As[64 * 64];
  __shared__ unsigned short Bs[128 * 64];
  int z = blockIdx.z;
  const float SCALE2 = 0.125f * 1.44269504089f;
  gemm_body<false, true, false, 64>(z ? (const void*)A1 : (const void*)A0, z ? B1 : B0,
                                    z ? bias1 : bias0, nullptr,
                                    nullptr, z ? o16_1 : o16_0, nullptr,
                                    nullptr, nullptr, nullptr,
                                    z ? 1.0f : SCALE2, M, N, K, As, Bs);
}

// ---------------- Flash attention (swapped QK^T, permuted V, register P) ----------
// O(bf16) = Qp/SCALE2 + softmax(Qp Kp^T) Vp.  dh=64, H=16, S=2048, D=1024.
// Qp16 PRE-SCALED by 0.125*log2(e); VpT columns PRE-PERMUTED (PV A-frag = own sacc).
// grid 512 (XCD-swizzled), 512 threads = 8 waves x 16 q-rows (QBLK=128).
// KVSTAGE=256: one barrier-pair per 256 k (staged in 64 KB LDS, free at the
// grid-limited 2 blocks/CU); compute runs two 128-k passes reusing sacc[8]/pf[4]
// so VGPR stays flat.
__global__ __launch_bounds__(512) void attn_kernel(const unsigned short* __restrict__ Qp,
                                                   const unsigned short* __restrict__ Kp,
                                                   const unsigned short* __restrict__ VpT,
                                                   unsigned short* __restrict__ O) {
  const int S = 2048, D = 1024;
  __shared__ unsigned short Ks[256 * 64];   // K[k][d], XOR-swizzled chunks (32 KB)
  __shared__ unsigned short Vs[64 * 256];   // V^T[d][kperm], XOR-swizzled (32 KB)
  const int id = blockIdx.x;
  const int swz = (id & 7) * 64 + (id >> 3);    // bijective, 512 % 8 == 0
  const int bh = swz >> 4, qt = swz & 15;       // 32 bh x 16 q-tiles of 128
  const int b = bh >> 4, h = bh & 15;
  const int tid = threadIdx.x, lane = tid & 63, w = tid >> 6;
  const int lr = lane & 15, lg = lane >> 4;
  const int xs = lr & 7;
  const size_t base = (size_t)(b * S) * D + h * 64;
  const size_t vbase = (size_t)(bh * 64) * S;   // VpT rows: (b*16+h)*64 + d
  const int q0 = qt * 128 + w * 16;
  const float INV_SCALE2 = 1.0f / (0.125f * 1.44269504089f);

  short8 qf[2];
#pragma unroll
  for (int ks = 0; ks < 2; ++ks)
    qf[ks] = *(const short8*)(Qp + base + (size_t)(q0 + lr) * D + ks * 32 + lg * 8);

  f32x4 oacc[4] = {};
  float m2 = -1e30f, lsum = 0.f;

  for (int kt = 0; kt < S; kt += 256) {
    // stage K tile [256 k][64 d] and V^T tile [64 d][256 kperm], both gload_lds
#pragma unroll
    for (int i = 0; i < 4; ++i) {
      int c = tid + i * 512;            // chunk 0..2047
      int rk = c >> 3, pck = c & 7;     // Ks: 8 chunks/row
      int lck = pck ^ (rk & 7);
      gload_lds16(Kp + base + (size_t)(kt + rk) * D + lck * 8, Ks + c * 8);
      int rv = c >> 5, pcv = c & 31;    // Vs: 32 chunks/row
      int lcv = (pcv & ~7) | ((pcv & 7) ^ (rv & 7));
      gload_lds16(VpT + vbase + (size_t)rv * S + kt + lcv * 8, Vs + c * 8);
    }
    __syncthreads();

    // two 128-k compute passes over the staged 256-k tile (sacc/pf reused)
#pragma unroll
    for (int half = 0; half < 2; ++half) {
      const int ko = half * 128;        // k-offset within staged tile

      // S^T = K Q^T : rows k (ko + nf*16+...), cols q (lr); log2 domain
      f32x4 sacc[8];
#pragma unroll
      for (int nf = 0; nf < 8; ++nf) sacc[nf] = (f32x4){0.f, 0.f, 0.f, 0.f};
      __builtin_amdgcn_s_setprio(1);
#pragma unroll
      for (int ks = 0; ks < 2; ++ks) {
#pragma unroll
        for (int nf = 0; nf < 8; ++nf) {
          short8 kf = *(const short8*)(Ks + (ko + nf * 16 + lr) * 64 +
                                       (((ks * 4 + lg) ^ xs) << 3));
          sacc[nf] = __builtin_amdgcn_mfma_f32_16x16x32_bf16(kf, qf[ks], sacc[nf], 0, 0, 0);
        }
      }
      __builtin_amdgcn_s_setprio(0);

      // in-register online softmax over 128 k (defer-max, THR=8, log2 domain)
      float sm = sacc[0][0];
#pragma unroll
      for (int nf = 0; nf < 8; ++nf)
#pragma unroll
        for (int r = 0; r < 4; ++r) sm = fmaxf(sm, sacc[nf][r]);
      sm = fmaxf(sm, __shfl_xor(sm, 16));
      sm = fmaxf(sm, __shfl_xor(sm, 32));
      if (__any(sm > m2 + 8.0f)) {
        float m2n = fmaxf(m2, sm);
        float alpha = __builtin_amdgcn_exp2f(m2 - m2n);
        m2 = m2n;
        lsum *= alpha;
        float a0 = __shfl(alpha, lg * 4 + 0);
        float a1 = __shfl(alpha, lg * 4 + 1);
        float a2 = __shfl(alpha, lg * 4 + 2);
        float a3 = __shfl(alpha, lg * 4 + 3);
#pragma unroll
        for (int dblk = 0; dblk < 4; ++dblk) {
          oacc[dblk][0] *= a0; oacc[dblk][1] *= a1;
          oacc[dblk][2] *= a2; oacc[dblk][3] *= a3;
        }
      }
      // exp + pack P into registers (A-fragment order; V column-permuted to match)
      float rsum = 0.f;
      short8 pf[4];
#pragma unroll
      for (int nf = 0; nf < 8; ++nf) {
        float p0 = __builtin_amdgcn_exp2f(sacc[nf][0] - m2);
        float p1 = __builtin_amdgcn_exp2f(sacc[nf][1] - m2);
        float p2 = __builtin_amdgcn_exp2f(sacc[nf][2] - m2);
        float p3 = __builtin_amdgcn_exp2f(sacc[nf][3] - m2);
        rsum += (p0 + p1) + (p2 + p3);
        int ks = nf >> 1, e0 = (nf & 1) * 4;
        pf[ks][e0 + 0] = (short)f32_to_bf16(p0);
        pf[ks][e0 + 1] = (short)f32_to_bf16(p1);
        pf[ks][e0 + 2] = (short)f32_to_bf16(p2);
        pf[ks][e0 + 3] = (short)f32_to_bf16(p3);
      }
      rsum += __shfl_xor(rsum, 16);
      rsum += __shfl_xor(rsum, 32);
      lsum += rsum;

      // PV: O += P V over this 128-k half (P in registers; V pre-permuted)
      __builtin_amdgcn_s_setprio(1);
#pragma unroll
      for (int ks = 0; ks < 4; ++ks) {
        int ch = (ko >> 3) + ks * 4 + lg;            // logical chunk 0..31
        int chv = (ch & ~7) | ((ch & 7) ^ xs);       // swizzled chunk
#pragma unroll
        for (int dblk = 0; dblk < 4; ++dblk) {
          short8 vf = *(const short8*)(Vs + (dblk * 16 + lr) * 256 + (chv << 3));
          oacc[dblk] = __builtin_amdgcn_mfma_f32_16x16x32_bf16(pf[ks], vf, oacc[dblk], 0, 0, 0);
        }
      }
      __builtin_amdgcn_s_setprio(0);
    }
    __syncthreads();  // all waves done reading Ks/Vs before restage
  }

  float rinv = 1.0f / lsum;
  float r0 = __shfl(rinv, lg * 4 + 0);
  float r1 = __shfl(rinv, lg * 4 + 1);
  float r2 = __shfl(rinv, lg * 4 + 2);
  float r3 = __shfl(rinv, lg * 4 + 3);
#pragma unroll
  for (int dblk = 0; dblk < 4; ++dblk) {
    float rr[4] = {r0, r1, r2, r3};
#pragma unroll
    for (int j = 0; j < 4; ++j) {
      size_t idx = base + (size_t)(q0 + lg * 4 + j) * D + dblk * 16 + lr;
      float qres = bf16_to_f32(Qp[idx]) * INV_SCALE2;
      O[idx] = f32_to_bf16(qres + oacc[dblk][j] * rr[j]);
    }
  }
}

// ---------------- LayerNorm stats over D=1024 (bf16 in) -> per-row {mu, rs} ------
// Reduction code IDENTICAL to ln_bf16_kernel so mu/rs are bit-identical.
__global__ __launch_bounds__(256) void ln_stats_kernel(const unsigned short* __restrict__ X,
                                                       float2* __restrict__ MR) {
  const int D = 1024;
  int row = blockIdx.x;
  int t = threadIdx.x;
  ushort4 xu = *(const ushort4*)(X + (size_t)row * D + t * 4);
  float4 v;
  v.x = bf16_to_f32(xu.x); v.y = bf16_to_f32(xu.y);
  v.z = bf16_to_f32(xu.z); v.w = bf16_to_f32(xu.w);
  float s = v.x + v.y + v.z + v.w;
  float s2 = v.x * v.x + v.y * v.y + v.z * v.z + v.w * v.w;
#pragma unroll
  for (int off = 1; off < 64; off <<= 1) {
    s += __shfl_xor(s, off, 64);
    s2 += __shfl_xor(s2, off, 64);
  }
  __shared__ float red[8];
  int wid = t >> 6, lane = t & 63;
  if (lane == 0) { red[wid] = s; red[4 + wid] = s2; }
  __syncthreads();
  s = red[0] + red[1] + red[2] + red[3];
  s2 = red[4] + red[5] + red[6] + red[7];
  float mu = s * (1.f / 1024.f);
  float var = s2 * (1.f / 1024.f) - mu * mu;
  float rs = rsqrtf(var + 1e-5f);
  if (t == 0) {
    float2 m; m.x = mu; m.y = rs;
    MR[row] = m;
  }
}

// ---------------- LayerNorm over D=1024 (bf16 in, bf16/f32 out), one block/row ---
__global__ __launch_bounds__(256) void ln_bf16_kernel(const unsigned short* __restrict__ X,
                                                      const float* __restrict__ g,
                                                      const float* __restrict__ bta,
                                                      unsigned short* __restrict__ out16,
                                                      float* __restrict__ out32) {
  const int D = 1024;
  int row = blockIdx.x;
  int t = threadIdx.x;
  ushort4 xu = *(const ushort4*)(X + (size_t)row * D + t * 4);
  float4 v;
  v.x = bf16_to_f32(xu.x); v.y = bf16_to_f32(xu.y);
  v.z = bf16_to_f32(xu.z); v.w = bf16_to_f32(xu.w);
  float s = v.x + v.y + v.z + v.w;
  float s2 = v.x * v.x + v.y * v.y + v.z * v.z + v.w * v.w;
#pragma unroll
  for (int off = 1; off < 64; off <<= 1) {
    s += __shfl_xor(s, off, 64);
    s2 += __shfl_xor(s2, off, 64);
  }
  __shared__ float red[8];
  int wid = t >> 6, lane = t & 63;
  if (lane == 0) { red[wid] = s; red[4 + wid] = s2; }
  __syncthreads();
  s = red[0] + red[1] + red[2] + red[3];
  s2 = red[4] + red[5] + red[6] + red[7];
  float mu = s * (1.f / 1024.f);
  float var = s2 * (1.f / 1024.f) - mu * mu;
  float rs = rsqrtf(var + 1e-5f);
  float4 gv = *(const float4*)(g + t * 4);
  float4 bv = *(const float4*)(bta + t * 4);
  float4 o;
  o.x = (v.x - mu) * rs * gv.x + bv.x;
  o.y = (v.y - mu) * rs * gv.y + bv.y;
  o.z = (v.z - mu) * rs * gv.z + bv.z;
  o.w = (v.w - mu) * rs * gv.w + bv.w;
  if (out16) {
    ushort4 h;
    h.x = f32_to_bf16(o.x); h.y = f32_to_bf16(o.y);
    h.z = f32_to_bf16(o.z); h.w = f32_to_bf16(o.w);
    *(ushort4*)(out16 + (size_t)row * D + t * 4) = h;
  }
  if (out32) *(float4*)(out32 + (size_t)row * D + t * 4) = o;
}

extern "C" void kernel_launch(void* const* d_in, const int* in_sizes, int n_in,
                              void* d_out, int out_size, void* d_ws, size_t ws_size,
                              hipStream_t stream) {
  const float* Q = (const float*)d_in[0];
  const float* K = (const float*)d_in[1];
  const float* Wq = (const float*)d_in[2];
  const float* bq = (const float*)d_in[3];
  const float* Wk = (const float*)d_in[4];
  const float* bk = (const float*)d_in[5];
  const float* Wv = (const float*)d_in[6];
  const float* bv = (const float*)d_in[7];
  const float* Wo = (const float*)d_in[8];
  const float* bo = (const float*)d_in[9];
  const float* g0 = (const float*)d_in[10];
  const float* b0 = (const float*)d_in[11];
  const float* g1 = (const float*)d_in[12];
  const float* b1 = (const float*)d_in[13];
  float* out = (float*)d_out;

  const int M = 4096, D = 1024;
  char* p = (char*)d_ws;
  auto alloc = [&](size_t n) { char* r = p; p += (n + 255) & ~(size_t)255; return r; };
  unsigned short* WqT = (unsigned short*)alloc((size_t)D * D * 2);
  unsigned short* WkT = (unsigned short*)alloc((size_t)D * D * 2);
  unsigned short* WvT = (unsigned short*)alloc((size_t)D * D * 2);
  unsigned short* WoT = (unsigned short*)alloc((size_t)D * D * 2);
  unsigned short* Qp16 = (unsigned short*)alloc((size_t)M * D * 2);  // scaled by SCALE2
  unsigned short* Kp16 = (unsigned short*)alloc((size_t)M * D * 2);
  unsigned short* VpT = (unsigned short*)alloc((size_t)M * D * 2);   // [B*H*64][2048] perm
  unsigned short* O16 = (unsigned short*)alloc((size_t)M * D * 2);   // attn out bf16
  unsigned short* O2_16 = (unsigned short*)alloc((size_t)M * D * 2); // Wo out bf16
  float2* MR = (float2*)alloc((size_t)M * sizeof(float2));           // ln0 {mu, rs}

  transpose4_kernel<<<dim3(32, 32, 4), dim3(32, 8), 0, stream>>>(Wq, Wk, Wv, Wo,
                                                                 WqT, WkT, WvT, WoT);

  dim3 gg(M / 64, D / 128);
  gemm_qk_kernel<<<dim3(M / 64, D / 128, 2), dim3(512), 0, stream>>>(
      Q, K, WqT, WkT, bq, bk, Qp16, Kp16, M, D, D);
  gemm_kernel<false><<<gg, dim3(512), 0, stream>>>(Kp16, WvT, bv, nullptr, nullptr, nullptr,
                                                   VpT, M, D, D);

  attn_kernel<<<dim3(512), dim3(512), 0, stream>>>(Qp16, Kp16, VpT, O16);

  ln_stats_kernel<<<dim3(M), dim3(256), 0, stream>>>(O16, MR);
  gemm_lnwo_kernel<<<gg, dim3(512), 0, stream>>>(O16, WoT, bo, O2_16, MR, g0, b0,
                                                 M, D, D);
  ln_bf16_kernel<<<dim3(M), dim3(256), 0, stream>>>(O2_16, g1, b1, nullptr, out);
}

// Round 40
// 130.242 us; speedup vs baseline: 1.0584x; 1.0584x over previous
//
#include <hip/hip_runtime.h>
#include <hip/hip_bf16.h>

typedef __attribute__((ext_vector_type(8))) short short8;
typedef __attribute__((ext_vector_type(4))) float f32x4;
typedef __attribute__((ext_vector_type(8))) unsigned short ushort8;

__device__ __forceinline__ unsigned short f32_to_bf16(float f) {
  return __builtin_bit_cast(unsigned short, __float2bfloat16(f));
}
__device__ __forceinline__ float bf16_to_f32(unsigned short u) {
  return __builtin_bit_cast(float, (unsigned)u << 16);
}

// global -> LDS direct async copy, 16 B per lane
__device__ __forceinline__ void gload_lds16(const unsigned short* g, unsigned short* l) {
  __builtin_amdgcn_global_load_lds((const __attribute__((address_space(1))) void*)g,
                                   (__attribute__((address_space(3))) void*)l, 16, 0, 0);
}

// ---------------- fused W [K][N] f32 -> WT [N][K] bf16, 4 weights ----------------
__global__ __launch_bounds__(256) void transpose4_kernel(const float* __restrict__ W0,
                                                         const float* __restrict__ W1,
                                                         const float* __restrict__ W2,
                                                         const float* __restrict__ W3,
                                                         unsigned short* __restrict__ T0,
                                                         unsigned short* __restrict__ T1,
                                                         unsigned short* __restrict__ T2,
                                                         unsigned short* __restrict__ T3) {
  __shared__ float t[32][33];
  const int D = 1024;
  const float* Ws[4] = {W0, W1, W2, W3};
  unsigned short* Ts[4] = {T0, T1, T2, T3};
  const float* W = Ws[blockIdx.z];
  unsigned short* WT = Ts[blockIdx.z];
  int bx = blockIdx.x, by = blockIdx.y;
  int tx = threadIdx.x, ty = threadIdx.y;
#pragma unroll
  for (int i = 0; i < 4; ++i)
    t[ty * 4 + i][tx] = W[(size_t)(by * 32 + ty * 4 + i) * D + bx * 32 + tx];
  __syncthreads();
#pragma unroll
  for (int i = 0; i < 4; ++i) {
    int r = ty * 4 + i;
    WT[(size_t)(bx * 32 + r) * D + by * 32 + tx] = f32_to_bf16(t[tx][r]);
  }
}

// ---------------- GEMM body: C[M][N] = A[M][K] @ Bt[N][K]^T + bias ----------------
// BM=64 x BN=128 tile, 512 threads = 8 waves (wm: 2 x 32 rows, wn: 4 x 32 cols).
// BK: K-step (64 or 128). BK=128 halves barrier count; use on grid-limited GEMMs.
// A_F32: A is raw f32; staged via reg + RNE cvt + ds_write (same swizzled layout).
// GELU_RES: out = res16(bf16) + gelu(C+bias).
// o16_scale: multiplied into the bf16 output only.
// outT (optional): bf16 head-transposed V output with PV-fragment column permutation:
//   within each 64-block, k -> (nf>>1)*32 + lg*8 + (nf&1)*4 + j  (nf=k>>4, lg=(k>>2)&3, j=k&3)
template <bool GELU_RES, bool A_F32, int BK>
__device__ __forceinline__ void gemm_body(const void* __restrict__ Av,
                                          const unsigned short* __restrict__ Bt,
                                          const float* __restrict__ bias,
                                          const unsigned short* __restrict__ res16,
                                          float* __restrict__ out32,
                                          unsigned short* __restrict__ out16,
                                          unsigned short* __restrict__ outT,
                                          float o16_scale,
                                          int M, int N, int K,
                                          unsigned short* As, unsigned short* Bs) {
  const int tid = threadIdx.x;
  const int lane = tid & 63, wid = tid >> 6;
  const int wm = wid >> 2, wn = wid & 3;
  const int m0 = blockIdx.x * 64, n0 = blockIdx.y * 128;
  const int lr = lane & 15, lg = lane >> 4;
  const int xs = lr & 7;
  const int CPR = BK / 8;                // 16B chunks per row
  f32x4 acc[2][2] = {};
  for (int kt = 0; kt < K; kt += BK) {
#pragma unroll
    for (int i = 0; i < (128 * CPR) / 512; ++i) {  // B: 128 rows x CPR chunks
      int c = tid + i * 512;
      int r = c / CPR, pc = c % CPR;
      int lc = (pc & ~7) | ((pc & 7) ^ (r & 7));
      gload_lds16(Bt + (size_t)(n0 + r) * K + kt + lc * 8, Bs + c * 8);
    }
#pragma unroll
    for (int i = 0; i < (64 * CPR) / 512; ++i) {   // A: 64 rows x CPR chunks
      int c = tid + i * 512;
      int r = c / CPR, pc = c % CPR;
      int lc = (pc & ~7) | ((pc & 7) ^ (r & 7));
      if (A_F32) {
        const float* src = (const float*)Av + (size_t)(m0 + r) * K + kt + lc * 8;
        float4 f0 = *(const float4*)(src);
        float4 f1 = *(const float4*)(src + 4);
        ushort8 o;
        o[0] = f32_to_bf16(f0.x); o[1] = f32_to_bf16(f0.y);
        o[2] = f32_to_bf16(f0.z); o[3] = f32_to_bf16(f0.w);
        o[4] = f32_to_bf16(f1.x); o[5] = f32_to_bf16(f1.y);
        o[6] = f32_to_bf16(f1.z); o[7] = f32_to_bf16(f1.w);
        *(ushort8*)(As + c * 8) = o;
      } else {
        gload_lds16((const unsigned short*)Av + (size_t)(m0 + r) * K + kt + lc * 8,
                    As + c * 8);
      }
    }
    __syncthreads();
#pragma unroll
    for (int ks = 0; ks < BK / 32; ++ks) {
      short8 af[2], bfr[2];
      int ch = ks * 4 + lg;                        // logical chunk 0..CPR-1
      int chs = (ch & ~7) | ((ch & 7) ^ xs);       // swizzled chunk
#pragma unroll
      for (int mf = 0; mf < 2; ++mf)
        af[mf] = *(const short8*)(As + (wm * 32 + mf * 16 + lr) * BK + (chs << 3));
#pragma unroll
      for (int nf = 0; nf < 2; ++nf)
        bfr[nf] = *(const short8*)(Bs + (wn * 32 + nf * 16 + lr) * BK + (chs << 3));
#pragma unroll
      for (int mf = 0; mf < 2; ++mf)
#pragma unroll
        for (int nf = 0; nf < 2; ++nf)
          acc[mf][nf] = __builtin_amdgcn_mfma_f32_16x16x32_bf16(af[mf], bfr[nf], acc[mf][nf], 0, 0, 0);
    }
    __syncthreads();
  }
#pragma unroll
  for (int nf = 0; nf < 2; ++nf) {
    int cn = n0 + wn * 32 + nf * 16 + lr;
    float bv = bias[cn];
#pragma unroll
    for (int mf = 0; mf < 2; ++mf) {
      int rm0 = m0 + wm * 32 + mf * 16 + lg * 4;
      float vv[4];
#pragma unroll
      for (int j = 0; j < 4; ++j) {
        float v = acc[mf][nf][j] + bv;
        if (GELU_RES) {
          float g = 0.5f * v * (1.0f + erff(v * 0.70710678118f));
          v = bf16_to_f32(res16[(size_t)(rm0 + j) * N + cn]) + g;
        }
        vv[j] = v;
        if (out32) out32[(size_t)(rm0 + j) * N + cn] = v;
        if (out16) out16[(size_t)(rm0 + j) * N + cn] = f32_to_bf16(v * o16_scale);
      }
      if (outT) {
        // C^T[cn][rm0..rm0+3] -> VpT[(b*16+h)*64+d][kperm], b=rm>>11, k=rm&2047
        int bb = rm0 >> 11, kk = rm0 & 2047;
        int hh = cn >> 6, dd = cn & 63;
        int kin = kk & 63, kb = kk & ~63;
        int nfk = kin >> 4, lgk = (kin >> 2) & 3;
        int kperm = kb + (nfk >> 1) * 32 + lgk * 8 + (nfk & 1) * 4;
        ushort4 tv;
        tv.x = f32_to_bf16(vv[0]); tv.y = f32_to_bf16(vv[1]);
        tv.z = f32_to_bf16(vv[2]); tv.w = f32_to_bf16(vv[3]);
        *(ushort4*)(outT + ((size_t)((bb * 16 + hh) * 64 + dd)) * 2048 + kperm) = tv;
      }
    }
  }
}

// BK=128 variant: used for Wv / Wo GEMMs (grid 512 = 2 blocks/CU, grid-limited,
// so the 48 KB LDS costs no occupancy; barriers per K-loop halve).
template <bool GELU_RES>
__global__ __launch_bounds__(512) void gemm_kernel(const unsigned short* __restrict__ A,
                                                   const unsigned short* __restrict__ Bt,
                                                   const float* __restrict__ bias,
                                                   const unsigned short* __restrict__ res16,
                                                   float* __restrict__ out32,
                                                   unsigned short* __restrict__ out16,
                                                   unsigned short* __restrict__ outT,
                                                   int M, int N, int K) {
  __shared__ unsigned short As[64 * 128];
  __shared__ unsigned short Bs[128 * 128];
  gemm_body<GELU_RES, false, 128>(A, Bt, bias, res16, out32, out16, outT, 1.0f,
                                  M, N, K, As, Bs);
}

// fused Q-proj + K-proj reading RAW f32 Q/K (conversion fused into A-staging);
// BK=64 (grid 1024 = 4 blocks/CU wants small LDS).
// Q's bf16 output pre-scaled by 0.125*log2(e) for attn (residual recovered by /SCALE2).
__global__ __launch_bounds__(512) void gemm_qk_kernel(const float* __restrict__ A0,
                                                      const float* __restrict__ A1,
                                                      const unsigned short* __restrict__ B0,
                                                      const unsigned short* __restrict__ B1,
                                                      const float* __restrict__ bias0,
                                                      const float* __restrict__ bias1,
                                                      unsigned short* __restrict__ o16_0,
                                                      unsigned short* __restrict__ o16_1,
                                                      int M, int N, int K) {
  __shared__ unsigned short As[64 * 64];
  __shared__ unsigned short Bs[128 * 64];
  int z = blockIdx.z;
  const float SCALE2 = 0.125f * 1.44269504089f;
  gemm_body<false, true, 64>(z ? (const void*)A1 : (const void*)A0, z ? B1 : B0,
                             z ? bias1 : bias0, nullptr,
                             nullptr, z ? o16_1 : o16_0, nullptr,
                             z ? 1.0f : SCALE2, M, N, K, As, Bs);
}

// ---------------- Flash attention (swapped QK^T, permuted V, register P) ----------
// O(bf16) = Qp/SCALE2 + softmax(Qp Kp^T) Vp.  dh=64, H=16, S=2048, D=1024.
// Qp16 PRE-SCALED by 0.125*log2(e); VpT columns PRE-PERMUTED (PV A-frag = own sacc).
// grid 512 (XCD-swizzled), 512 threads = 8 waves x 16 q-rows (QBLK=128).
// KVSTAGE=256: one barrier-pair per 256 k (staged in 64 KB LDS, free at the
// grid-limited 2 blocks/CU); compute runs two 128-k passes reusing sacc[8]/pf[4]
// so VGPR stays flat.
__global__ __launch_bounds__(512) void attn_kernel(const unsigned short* __restrict__ Qp,
                                                   const unsigned short* __restrict__ Kp,
                                                   const unsigned short* __restrict__ VpT,
                                                   unsigned short* __restrict__ O) {
  const int S = 2048, D = 1024;
  __shared__ unsigned short Ks[256 * 64];   // K[k][d], XOR-swizzled chunks (32 KB)
  __shared__ unsigned short Vs[64 * 256];   // V^T[d][kperm], XOR-swizzled (32 KB)
  const int id = blockIdx.x;
  const int swz = (id & 7) * 64 + (id >> 3);    // bijective, 512 % 8 == 0
  const int bh = swz >> 4, qt = swz & 15;       // 32 bh x 16 q-tiles of 128
  const int b = bh >> 4, h = bh & 15;
  const int tid = threadIdx.x, lane = tid & 63, w = tid >> 6;
  const int lr = lane & 15, lg = lane >> 4;
  const int xs = lr & 7;
  const size_t base = (size_t)(b * S) * D + h * 64;
  const size_t vbase = (size_t)(bh * 64) * S;   // VpT rows: (b*16+h)*64 + d
  const int q0 = qt * 128 + w * 16;
  const float INV_SCALE2 = 1.0f / (0.125f * 1.44269504089f);

  short8 qf[2];
#pragma unroll
  for (int ks = 0; ks < 2; ++ks)
    qf[ks] = *(const short8*)(Qp + base + (size_t)(q0 + lr) * D + ks * 32 + lg * 8);

  f32x4 oacc[4] = {};
  float m2 = -1e30f, lsum = 0.f;

  for (int kt = 0; kt < S; kt += 256) {
    // stage K tile [256 k][64 d] and V^T tile [64 d][256 kperm], both gload_lds
#pragma unroll
    for (int i = 0; i < 4; ++i) {
      int c = tid + i * 512;            // chunk 0..2047
      int rk = c >> 3, pck = c & 7;     // Ks: 8 chunks/row
      int lck = pck ^ (rk & 7);
      gload_lds16(Kp + base + (size_t)(kt + rk) * D + lck * 8, Ks + c * 8);
      int rv = c >> 5, pcv = c & 31;    // Vs: 32 chunks/row
      int lcv = (pcv & ~7) | ((pcv & 7) ^ (rv & 7));
      gload_lds16(VpT + vbase + (size_t)rv * S + kt + lcv * 8, Vs + c * 8);
    }
    __syncthreads();

    // two 128-k compute passes over the staged 256-k tile (sacc/pf reused)
#pragma unroll
    for (int half = 0; half < 2; ++half) {
      const int ko = half * 128;        // k-offset within staged tile

      // S^T = K Q^T : rows k (ko + nf*16+...), cols q (lr); log2 domain
      f32x4 sacc[8];
#pragma unroll
      for (int nf = 0; nf < 8; ++nf) sacc[nf] = (f32x4){0.f, 0.f, 0.f, 0.f};
      __builtin_amdgcn_s_setprio(1);
#pragma unroll
      for (int ks = 0; ks < 2; ++ks) {
#pragma unroll
        for (int nf = 0; nf < 8; ++nf) {
          short8 kf = *(const short8*)(Ks + (ko + nf * 16 + lr) * 64 +
                                       (((ks * 4 + lg) ^ xs) << 3));
          sacc[nf] = __builtin_amdgcn_mfma_f32_16x16x32_bf16(kf, qf[ks], sacc[nf], 0, 0, 0);
        }
      }
      __builtin_amdgcn_s_setprio(0);

      // in-register online softmax over 128 k (defer-max, THR=8, log2 domain)
      float sm = sacc[0][0];
#pragma unroll
      for (int nf = 0; nf < 8; ++nf)
#pragma unroll
        for (int r = 0; r < 4; ++r) sm = fmaxf(sm, sacc[nf][r]);
      sm = fmaxf(sm, __shfl_xor(sm, 16));
      sm = fmaxf(sm, __shfl_xor(sm, 32));
      if (__any(sm > m2 + 8.0f)) {
        float m2n = fmaxf(m2, sm);
        float alpha = __builtin_amdgcn_exp2f(m2 - m2n);
        m2 = m2n;
        lsum *= alpha;
        float a0 = __shfl(alpha, lg * 4 + 0);
        float a1 = __shfl(alpha, lg * 4 + 1);
        float a2 = __shfl(alpha, lg * 4 + 2);
        float a3 = __shfl(alpha, lg * 4 + 3);
#pragma unroll
        for (int dblk = 0; dblk < 4; ++dblk) {
          oacc[dblk][0] *= a0; oacc[dblk][1] *= a1;
          oacc[dblk][2] *= a2; oacc[dblk][3] *= a3;
        }
      }
      // exp + pack P into registers (A-fragment order; V column-permuted to match)
      float rsum = 0.f;
      short8 pf[4];
#pragma unroll
      for (int nf = 0; nf < 8; ++nf) {
        float p0 = __builtin_amdgcn_exp2f(sacc[nf][0] - m2);
        float p1 = __builtin_amdgcn_exp2f(sacc[nf][1] - m2);
        float p2 = __builtin_amdgcn_exp2f(sacc[nf][2] - m2);
        float p3 = __builtin_amdgcn_exp2f(sacc[nf][3] - m2);
        rsum += (p0 + p1) + (p2 + p3);
        int ks = nf >> 1, e0 = (nf & 1) * 4;
        pf[ks][e0 + 0] = (short)f32_to_bf16(p0);
        pf[ks][e0 + 1] = (short)f32_to_bf16(p1);
        pf[ks][e0 + 2] = (short)f32_to_bf16(p2);
        pf[ks][e0 + 3] = (short)f32_to_bf16(p3);
      }
      rsum += __shfl_xor(rsum, 16);
      rsum += __shfl_xor(rsum, 32);
      lsum += rsum;

      // PV: O += P V over this 128-k half (P in registers; V pre-permuted)
      __builtin_amdgcn_s_setprio(1);
#pragma unroll
      for (int ks = 0; ks < 4; ++ks) {
        int ch = (ko >> 3) + ks * 4 + lg;            // logical chunk 0..31
        int chv = (ch & ~7) | ((ch & 7) ^ xs);       // swizzled chunk
#pragma unroll
        for (int dblk = 0; dblk < 4; ++dblk) {
          short8 vf = *(const short8*)(Vs + (dblk * 16 + lr) * 256 + (chv << 3));
          oacc[dblk] = __builtin_amdgcn_mfma_f32_16x16x32_bf16(pf[ks], vf, oacc[dblk], 0, 0, 0);
        }
      }
      __builtin_amdgcn_s_setprio(0);
    }
    __syncthreads();  // all waves done reading Ks/Vs before restage
  }

  float rinv = 1.0f / lsum;
  float r0 = __shfl(rinv, lg * 4 + 0);
  float r1 = __shfl(rinv, lg * 4 + 1);
  float r2 = __shfl(rinv, lg * 4 + 2);
  float r3 = __shfl(rinv, lg * 4 + 3);
#pragma unroll
  for (int dblk = 0; dblk < 4; ++dblk) {
    float rr[4] = {r0, r1, r2, r3};
#pragma unroll
    for (int j = 0; j < 4; ++j) {
      size_t idx = base + (size_t)(q0 + lg * 4 + j) * D + dblk * 16 + lr;
      float qres = bf16_to_f32(Qp[idx]) * INV_SCALE2;
      O[idx] = f32_to_bf16(qres + oacc[dblk][j] * rr[j]);
    }
  }
}

// ---------------- LayerNorm over D=1024 (bf16 in, bf16/f32 out), one block/row ---
__global__ __launch_bounds__(256) void ln_bf16_kernel(const unsigned short* __restrict__ X,
                                                      const float* __restrict__ g,
                                                      const float* __restrict__ bta,
                                                      unsigned short* __restrict__ out16,
                                                      float* __restrict__ out32) {
  const int D = 1024;
  int row = blockIdx.x;
  int t = threadIdx.x;
  ushort4 xu = *(const ushort4*)(X + (size_t)row * D + t * 4);
  float4 v;
  v.x = bf16_to_f32(xu.x); v.y = bf16_to_f32(xu.y);
  v.z = bf16_to_f32(xu.z); v.w = bf16_to_f32(xu.w);
  float s = v.x + v.y + v.z + v.w;
  float s2 = v.x * v.x + v.y * v.y + v.z * v.z + v.w * v.w;
#pragma unroll
  for (int off = 1; off < 64; off <<= 1) {
    s += __shfl_xor(s, off, 64);
    s2 += __shfl_xor(s2, off, 64);
  }
  __shared__ float red[8];
  int wid = t >> 6, lane = t & 63;
  if (lane == 0) { red[wid] = s; red[4 + wid] = s2; }
  __syncthreads();
  s = red[0] + red[1] + red[2] + red[3];
  s2 = red[4] + red[5] + red[6] + red[7];
  float mu = s * (1.f / 1024.f);
  float var = s2 * (1.f / 1024.f) - mu * mu;
  float rs = rsqrtf(var + 1e-5f);
  float4 gv = *(const float4*)(g + t * 4);
  float4 bv = *(const float4*)(bta + t * 4);
  float4 o;
  o.x = (v.x - mu) * rs * gv.x + bv.x;
  o.y = (v.y - mu) * rs * gv.y + bv.y;
  o.z = (v.z - mu) * rs * gv.z + bv.z;
  o.w = (v.w - mu) * rs * gv.w + bv.w;
  if (out16) {
    ushort4 h;
    h.x = f32_to_bf16(o.x); h.y = f32_to_bf16(o.y);
    h.z = f32_to_bf16(o.z); h.w = f32_to_bf16(o.w);
    *(ushort4*)(out16 + (size_t)row * D + t * 4) = h;
  }
  if (out32) *(float4*)(out32 + (size_t)row * D + t * 4) = o;
}

extern "C" void kernel_launch(void* const* d_in, const int* in_sizes, int n_in,
                              void* d_out, int out_size, void* d_ws, size_t ws_size,
                              hipStream_t stream) {
  const float* Q = (const float*)d_in[0];
  const float* K = (const float*)d_in[1];
  const float* Wq = (const float*)d_in[2];
  const float* bq = (const float*)d_in[3];
  const float* Wk = (const float*)d_in[4];
  const float* bk = (const float*)d_in[5];
  const float* Wv = (const float*)d_in[6];
  const float* bv = (const float*)d_in[7];
  const float* Wo = (const float*)d_in[8];
  const float* bo = (const float*)d_in[9];
  const float* g0 = (const float*)d_in[10];
  const float* b0 = (const float*)d_in[11];
  const float* g1 = (const float*)d_in[12];
  const float* b1 = (const float*)d_in[13];
  float* out = (float*)d_out;

  const int M = 4096, D = 1024;
  char* p = (char*)d_ws;
  auto alloc = [&](size_t n) { char* r = p; p += (n + 255) & ~(size_t)255; return r; };
  unsigned short* WqT = (unsigned short*)alloc((size_t)D * D * 2);
  unsigned short* WkT = (unsigned short*)alloc((size_t)D * D * 2);
  unsigned short* WvT = (unsigned short*)alloc((size_t)D * D * 2);
  unsigned short* WoT = (unsigned short*)alloc((size_t)D * D * 2);
  unsigned short* Qp16 = (unsigned short*)alloc((size_t)M * D * 2);  // scaled by SCALE2
  unsigned short* Kp16 = (unsigned short*)alloc((size_t)M * D * 2);
  unsigned short* VpT = (unsigned short*)alloc((size_t)M * D * 2);   // [B*H*64][2048] perm
  unsigned short* O16 = (unsigned short*)alloc((size_t)M * D * 2);   // attn out bf16
  unsigned short* O1_16 = (unsigned short*)alloc((size_t)M * D * 2); // ln0 out bf16
  unsigned short* O2_16 = (unsigned short*)alloc((size_t)M * D * 2); // Wo out bf16

  transpose4_kernel<<<dim3(32, 32, 4), dim3(32, 8), 0, stream>>>(Wq, Wk, Wv, Wo,
                                                                 WqT, WkT, WvT, WoT);

  dim3 gg(M / 64, D / 128);
  gemm_qk_kernel<<<dim3(M / 64, D / 128, 2), dim3(512), 0, stream>>>(
      Q, K, WqT, WkT, bq, bk, Qp16, Kp16, M, D, D);
  gemm_kernel<false><<<gg, dim3(512), 0, stream>>>(Kp16, WvT, bv, nullptr, nullptr, nullptr,
                                                   VpT, M, D, D);

  attn_kernel<<<dim3(512), dim3(512), 0, stream>>>(Qp16, Kp16, VpT, O16);

  ln_bf16_kernel<<<dim3(M), dim3(256), 0, stream>>>(O16, g0, b0, O1_16, nullptr);
  gemm_kernel<true><<<gg, dim3(512), 0, stream>>>(O1_16, WoT, bo, O1_16, nullptr, O2_16,
                                                  nullptr, M, D, D);
  ln_bf16_kernel<<<dim3(M), dim3(256), 0, stream>>>(O2_16, g1, b1, nullptr, out);
}